// Round 5
// baseline (615.664 us; speedup 1.0000x reference)
//
#include <hip/hip_runtime.h>
#include <math.h>

// Problem constants: B=8, C=64, H=W=256, fp32 in/out.
constexpr int CH  = 64;      // channels
constexpr int WW  = 256;     // H == W
constexpr int HWS = WW * WW; // 65536 elements per (b,c) slab
constexpr int NB  = 8;       // batch

typedef __attribute__((ext_vector_type(8))) short bf16x8;
typedef __attribute__((ext_vector_type(4))) float f32x4;

// RNE fp32 -> bf16 (manual; data is finite)
__device__ inline ushort f2bf(float f) {
    uint u = __float_as_uint(f);
    u += 0x7fffu + ((u >> 16) & 1u);
    return (ushort)(u >> 16);
}

// Pack fp32 -> (bf16_hi << 16) | bf16_lo, hi = truncation, lo = trunc(f - hi).
__device__ inline uint packsplit(float f) {
    const uint fu = __float_as_uint(f);
    const float lo = f - __uint_as_float(fu & 0xffff0000u);
    return (fu & 0xffff0000u) | (__float_as_uint(lo) >> 16);
}

union FragU { uint u[4]; bf16x8 v; };

// ---------------------------------------------------------------------------
// Kernel 1: fused QKV projection via split-bf16 MFMA.
// NEW this round: block = 8h x 16i 2D pixel tile; Q,K stored in h-group-packed
// layout  Qt[c][h>>3][i][h&7]  (packed-split uint) via a 33KB LDS transpose
// (XOR pos swizzle, c-stride 132 => <=4-way banks) and 8 coalesced dwordx4
// stores per thread per matrix — replaces 96 scalar uint stores.  This makes
// attn fragments k-CONTIGUOUS (8 uints = 2 dwordx4).  V unchanged (pixel
// layout, feeds transpose_v/pv).
// ---------------------------------------------------------------------------
__global__ __launch_bounds__(256) void qkv_mfma2(
    const float* __restrict__ x,
    const float* __restrict__ Wq, const float* __restrict__ bq,
    const float* __restrict__ Wk, const float* __restrict__ bk,
    const float* __restrict__ Wv, const float* __restrict__ bv,
    uint* __restrict__ Q, uint* __restrict__ K, ushort* __restrict__ V)
{
    // 33792 B shared: staging planes (32KB) alias the transpose buffer.
    __shared__ uint SH[64 * 132] __attribute__((aligned(16)));
    ushort* Xhi = (ushort*)SH;            // [128px][64c] bf16-hi plane (16KB)
    ushort* Xlo = (ushort*)&SH[4096];     // [128px][64c] bf16-lo plane (16KB)

    const int tid  = threadIdx.x;
    const int ln   = tid & 63;
    const int wid  = tid >> 6;       // 0..3
    const int ml   = ln & 15;
    const int quad = ln >> 4;

    const int bid = blockIdx.x;
    const int b   = bid >> 9;              // 512 tiles per batch
    const int rr  = bid & 511;
    const int ht  = rr >> 4;               // 0..31 h-group tile
    const int it  = rr & 15;               // 0..15 i tile
    const int h0  = ht * 8;
    const int i0  = it * 16;
    const float* xb = x + ((size_t)(b * CH) << 16);

    // ---- A-fragments: W hi/lo into registers (3 m-tiles x 2 k-frags) ----
    bf16x8 Ah[3][2], Al[3][2];
    float biasv[3][4];
#pragma unroll
    for (int a = 0; a < 3; ++a) {
        const int mt = wid * 3 + a;                 // m-tile 0..11
        const float* Wsrc = (mt < 4) ? Wq : (mt < 8) ? Wk : Wv;
        const float* bsrc = (mt < 4) ? bq : (mt < 8) ? bk : bv;
        const int o = (mt & 3) * 16 + ml;           // output row within matrix
#pragma unroll
        for (int kf = 0; kf < 2; ++kf) {
            FragU Hh, Ll;
#pragma unroll
            for (int rp = 0; rp < 4; ++rp) {
                const float f0 = Wsrc[o * 64 + kf * 32 + quad * 8 + rp * 2];
                const float f1 = Wsrc[o * 64 + kf * 32 + quad * 8 + rp * 2 + 1];
                const uint u0 = __float_as_uint(f0);
                const uint u1 = __float_as_uint(f1);
                const float g0 = f0 - __uint_as_float(u0 & 0xffff0000u);
                const float g1 = f1 - __uint_as_float(u1 & 0xffff0000u);
                Hh.u[rp] = __builtin_amdgcn_perm(u1, u0, 0x07060302u);
                Ll.u[rp] = __builtin_amdgcn_perm(__float_as_uint(g1),
                                                 __float_as_uint(g0), 0x07060302u);
            }
            Ah[a][kf] = Hh.v; Al[a][kf] = Ll.v;
        }
#pragma unroll
        for (int r = 0; r < 4; ++r)
            biasv[a][r] = bsrc[(mt & 3) * 16 + quad * 4 + r];
    }

    // ---- Stage X: fp32 8h x 16i per c -> bf16 hi/lo planes [px][c] --------
    // px = hl*16 + il;  adr(px,c) = px*64 + ((c>>3 ^ (px>>1)&7)<<3) + (c&7)
#pragma unroll
    for (int p = 0; p < 8; ++p) {
        const int flat = p * 256 + tid;      // 0..2047
        const int c    = flat >> 5;          // 0..63
        const int hl   = (flat >> 2) & 7;
        const int i4   = (flat & 3) * 4;
        const float4 xv =
            *(const float4*)&xb[((size_t)c << 16) + (h0 + hl) * 256 + i0 + i4];
#pragma unroll
        for (int u = 0; u < 4; ++u) {
            const int px = hl * 16 + i4 + u;
            const float f = (&xv.x)[u];
            const uint fu = __float_as_uint(f);
            const float lo = f - __uint_as_float(fu & 0xffff0000u);
            const int adr = px * 64 + ((((c >> 3) ^ ((px >> 1) & 7))) << 3) + (c & 7);
            Xhi[adr] = (ushort)(fu >> 16);
            Xlo[adr] = (ushort)(__float_as_uint(lo) >> 16);
        }
    }
    __syncthreads();

    // ---- MFMA: 8 n-tiles x 3 m-tiles x 2 k-frags x 3 products -------------
    f32x4 acc[3][8];
    const f32x4 zero = {0.f, 0.f, 0.f, 0.f};
#pragma unroll
    for (int a = 0; a < 3; ++a)
#pragma unroll
        for (int t = 0; t < 8; ++t) acc[a][t] = zero;

#pragma unroll
    for (int t = 0; t < 8; ++t) {
        const int px = t * 16 + ml;
        bf16x8 Bh[2], Bl[2];
#pragma unroll
        for (int kf = 0; kf < 2; ++kf) {
            const int g   = kf * 4 + quad;
            const int adr = px * 64 + ((g ^ ((px >> 1) & 7)) << 3);
            Bh[kf] = *(const bf16x8*)&Xhi[adr];
            Bl[kf] = *(const bf16x8*)&Xlo[adr];
        }
#pragma unroll
        for (int a = 0; a < 3; ++a) {
#pragma unroll
            for (int kf = 0; kf < 2; ++kf) {
                acc[a][t] = __builtin_amdgcn_mfma_f32_16x16x32_bf16(Ah[a][kf], Bh[kf], acc[a][t], 0, 0, 0);
                acc[a][t] = __builtin_amdgcn_mfma_f32_16x16x32_bf16(Ah[a][kf], Bl[kf], acc[a][t], 0, 0, 0);
                acc[a][t] = __builtin_amdgcn_mfma_f32_16x16x32_bf16(Al[a][kf], Bh[kf], acc[a][t], 0, 0, 0);
            }
        }
    }

    // Thread's element (a,t,r): channel ch = (mt&3)*16 + quad*4 + r,
    // pixel (h = h0 + t, i = i0 + ml).
    // ---- V: direct stores (pixel layout, bf16) ----------------------------
#pragma unroll
    for (int a = 0; a < 3; ++a) {
        const int mt = wid * 3 + a;
        if (mt >= 8) {
            const int ch = (mt & 3) * 16 + quad * 4;
#pragma unroll
            for (int t = 0; t < 8; ++t)
#pragma unroll
                for (int r = 0; r < 4; ++r)
                    V[((size_t)(b * CH + ch + r) << 16) + (h0 + t) * 256 + i0 + ml] =
                        f2bf(acc[a][t][r] + biasv[a][r]);
        }
    }

    // ---- Q then K: LDS transpose -> coalesced dwordx4 stores --------------
    // Ts[ch][pos], c-stride 132, pos = il*8 + (t ^ (il&7))  (<=4-way banks)
    const int crd = tid >> 2;                 // read-pass channel 0..63
    const int ilc = (tid & 3) * 4;            // read-pass i-chunk base

#pragma unroll
    for (int mat = 0; mat < 2; ++mat) {       // 0 = Q, 1 = K
        __syncthreads();                      // LDS free (staging or prev pass)
#pragma unroll
        for (int a = 0; a < 3; ++a) {
            const int mt = wid * 3 + a;
            if ((mt >> 2) == mat) {           // Q: mt 0..3, K: mt 4..7
                const int ch = (mt & 3) * 16 + quad * 4;
#pragma unroll
                for (int r = 0; r < 4; ++r)
#pragma unroll
                    for (int t = 0; t < 8; ++t)
                        SH[(ch + r) * 132 + ml * 8 + (t ^ (ml & 7))] =
                            packsplit(acc[a][t][r] + biasv[a][r]);
            }
        }
        __syncthreads();
        uint* dstbase = (mat == 0) ? Q : K;
#pragma unroll
        for (int ii = 0; ii < 4; ++ii) {
            const int il = ilc + ii;
            uint tmp[8];
#pragma unroll
            for (int t = 0; t < 8; ++t)
                tmp[t] = SH[crd * 132 + il * 8 + (t ^ (il & 7))];
            uint* dst = dstbase + ((size_t)(b * CH + crd) << 16)
                        + ht * 2048 + (size_t)(i0 + il) * 8;
            *(uint4*)dst       = *(uint4*)&tmp[0];
            *(uint4*)(dst + 4) = *(uint4*)&tmp[4];
        }
    }
}

// ---------------------------------------------------------------------------
// Kernel 2: attn via split-bf16 MFMA, LDS-free, k-contiguous fragments.
// Qt/Kt layout [c][h>>3][i][h&7] (packed-split uint): one fragment = 8
// contiguous uints = 2x global_load_dwordx4 (16 loads/chunk vs 64 dword).
// ---------------------------------------------------------------------------
__global__ __launch_bounds__(256) void attn_mfma3(
    const uint* __restrict__ Qp, const uint* __restrict__ Kp,
    float* __restrict__ attn)
{
    const int gid = blockIdx.x;
    const int bc  = gid >> 2;
    const int i0  = ((gid >> 1) & 1) * 128;
    const int j0  = (gid & 1) * 128;
    const uint* q = Qp + (size_t)bc * HWS;
    const uint* k = Kp + (size_t)bc * HWS;
    float* out    = attn + (size_t)bc * HWS;

    const int tid  = threadIdx.x;
    const int L    = tid & 63;
    const int wid  = tid >> 6;
    const int wy   = (wid >> 1) * 64;
    const int wx   = (wid & 1) * 64;
    const int ml   = L & 15;
    const int quad = L >> 4;

    const f32x4 zero = {0.f, 0.f, 0.f, 0.f};
    f32x4 acc[4][4];
#pragma unroll
    for (int a = 0; a < 4; ++a)
#pragma unroll
        for (int b = 0; b < 4; ++b) acc[a][b] = zero;

    for (int k0 = 0; k0 < WW; k0 += 32) {
        // quad's h-group this chunk: (k0>>3) + quad; frag = 8 contiguous uints
        const size_t gb = (size_t)((k0 >> 3) + quad) * 2048;
        uint ua[4][8], ub[4][8];
#pragma unroll
        for (int a = 0; a < 4; ++a) {
            const uint* p = q + gb + (size_t)(i0 + wy + a * 16 + ml) * 8;
            *(uint4*)&ua[a][0] = *(const uint4*)p;
            *(uint4*)&ua[a][4] = *(const uint4*)(p + 4);
        }
#pragma unroll
        for (int b = 0; b < 4; ++b) {
            const uint* p = k + gb + (size_t)(j0 + wx + b * 16 + ml) * 8;
            *(uint4*)&ub[b][0] = *(const uint4*)p;
            *(uint4*)&ub[b][4] = *(const uint4*)(p + 4);
        }

        bf16x8 Ahf[4], Alf[4], Bhf[4], Blf[4];
#pragma unroll
        for (int a = 0; a < 4; ++a) {
            FragU H, Lo;
#pragma unroll
            for (int rp = 0; rp < 4; ++rp) {
                H.u[rp]  = __builtin_amdgcn_perm(ua[a][rp * 2 + 1], ua[a][rp * 2], 0x07060302u);
                Lo.u[rp] = __builtin_amdgcn_perm(ua[a][rp * 2 + 1], ua[a][rp * 2], 0x05040100u);
            }
            Ahf[a] = H.v; Alf[a] = Lo.v;
        }
#pragma unroll
        for (int b = 0; b < 4; ++b) {
            FragU H, Lo;
#pragma unroll
            for (int rp = 0; rp < 4; ++rp) {
                H.u[rp]  = __builtin_amdgcn_perm(ub[b][rp * 2 + 1], ub[b][rp * 2], 0x07060302u);
                Lo.u[rp] = __builtin_amdgcn_perm(ub[b][rp * 2 + 1], ub[b][rp * 2], 0x05040100u);
            }
            Bhf[b] = H.v; Blf[b] = Lo.v;
        }

#pragma unroll
        for (int a = 0; a < 4; ++a)
#pragma unroll
            for (int b = 0; b < 4; ++b) {
                acc[a][b] = __builtin_amdgcn_mfma_f32_16x16x32_bf16(Ahf[a], Bhf[b], acc[a][b], 0, 0, 0);
                acc[a][b] = __builtin_amdgcn_mfma_f32_16x16x32_bf16(Ahf[a], Blf[b], acc[a][b], 0, 0, 0);
                acc[a][b] = __builtin_amdgcn_mfma_f32_16x16x32_bf16(Alf[a], Bhf[b], acc[a][b], 0, 0, 0);
            }
    }

    // C/D layout: col = lane&15, row = quad*4 + reg
#pragma unroll
    for (int a = 0; a < 4; ++a)
#pragma unroll
        for (int b = 0; b < 4; ++b)
#pragma unroll
            for (int r = 0; r < 4; ++r)
                out[(size_t)(i0 + wy + a * 16 + quad * 4 + r) * WW
                    + j0 + wx + b * 16 + ml] = acc[a][b][r];
}

// ---------------------------------------------------------------------------
// Kernel 3: transpose V (bf16): Vt[b,c,j,m] = Vb[b,c,m,j].
// ---------------------------------------------------------------------------
__global__ __launch_bounds__(256) void transpose_v(
    const ushort* __restrict__ Vb, ushort* __restrict__ Vt)
{
    const int blk = blockIdx.x;
    const int bc  = blk >> 2;
    const int m0  = ((blk >> 1) & 1) * 128;
    const int j0  = (blk & 1) * 128;
    const ushort* src = Vb + (size_t)bc * HWS;
    ushort* dst       = Vt + (size_t)bc * HWS;

    __shared__ ushort T[128][128] __attribute__((aligned(16)));

    const int tid = threadIdx.x;
#pragma unroll
    for (int p = 0; p < 8; ++p) {
        const int id  = p * 256 + tid;
        const int mm  = id >> 4;
        const int c16 = id & 15;               // jj-group
        const int cg  = (c16 + (mm >> 3)) & 15;
        *(uint4*)&T[mm][cg * 8] =
            *(const uint4*)(src + (size_t)(m0 + mm) * WW + j0 + c16 * 8);
    }
    __syncthreads();
#pragma unroll
    for (int p = 0; p < 4; ++p) {
        const int id  = p * 256 + tid;
        const int c16 = id & 15;               // m-chunk (lane-fast => coalesced stores)
        const int jjp = id >> 4;               // 0..63 (row pair)
        const int jj  = jjp * 2;
        const int jjg = jj >> 3;
        ushort ra[8], rb[8];
#pragma unroll
        for (int u = 0; u < 8; ++u) {
            const int mm = c16 * 8 + u;        // mm>>3 == c16
            const int cg = (jjg + c16) & 15;
            const uint pr = *(const uint*)&T[mm][cg * 8 + (jj & 7)];
            ra[u] = (ushort)(pr & 0xffffu);
            rb[u] = (ushort)(pr >> 16);
        }
        *(uint4*)(dst + (size_t)(j0 + jj)     * WW + m0 + c16 * 8) = *(uint4*)ra;
        *(uint4*)(dst + (size_t)(j0 + jj + 1) * WW + m0 + c16 * 8) = *(uint4*)rb;
    }
}

// ---------------------------------------------------------------------------
// Kernel 4: channel softmax, fp32 logits in -> bf16 weights out.
// ---------------------------------------------------------------------------
__global__ __launch_bounds__(128) void softmax_kernel(
    const float* __restrict__ logits, ushort* __restrict__ Wb)
{
    const int gid = blockIdx.x;            // b*256 + i
    const int b   = gid >> 8;
    const int i   = gid & 255;
    const int j2  = threadIdx.x * 2;
    const size_t off = (((size_t)(b * CH)) << 16) + (size_t)i * WW + j2;
    const float* base = logits + off;
    ushort* wout      = Wb + off;

    float2 v[CH];
#pragma unroll
    for (int c = 0; c < CH; ++c) v[c] = *(const float2*)&base[((size_t)c) << 16];

    float mx = v[0].x, my = v[0].y;
#pragma unroll
    for (int c = 1; c < CH; ++c) { mx = fmaxf(mx, v[c].x); my = fmaxf(my, v[c].y); }

    float sx = 0.f, sy = 0.f;
#pragma unroll
    for (int c = 0; c < CH; ++c) {
        v[c].x = __expf(v[c].x - mx); sx += v[c].x;
        v[c].y = __expf(v[c].y - my); sy += v[c].y;
    }
    const float ix = 1.0f / sx, iy = 1.0f / sy;
#pragma unroll
    for (int c = 0; c < CH; ++c) {
        ushort2 o;
        o.x = f2bf(v[c].x * ix);
        o.y = f2bf(v[c].y * iy);
        *(ushort2*)&wout[((size_t)c) << 16] = o;
    }
}

// ---------------------------------------------------------------------------
// Kernel 5: PV via bf16 MFMA.  out[i][j] = sum_m w[i][m] * v[m][j], per (b,c).
// ---------------------------------------------------------------------------
__global__ __launch_bounds__(256) void pv_kernel2(
    const ushort* __restrict__ Wb, const ushort* __restrict__ Vt,
    float* __restrict__ out)
{
    const int blk = blockIdx.x;
    const int bc  = blk >> 2;
    const int i0  = ((blk >> 1) & 1) * 128;
    const int j0  = (blk & 1) * 128;
    const ushort* w  = Wb + (size_t)bc * HWS;
    const ushort* vt = Vt + (size_t)bc * HWS;
    float* o         = out + (size_t)bc * HWS;

    __shared__ ushort As[128][40] __attribute__((aligned(16)));
    __shared__ ushort Bs[128][40] __attribute__((aligned(16)));

    const int tid  = threadIdx.x;
    const int L    = tid & 63;
    const int wid  = tid >> 6;
    const int wy   = (wid >> 1) * 64;
    const int wx   = (wid & 1) * 64;
    const int ml   = L & 15;
    const int quad = L >> 4;

    f32x4 zero = {0.f, 0.f, 0.f, 0.f};
    f32x4 acc[4][4];
#pragma unroll
    for (int a = 0; a < 4; ++a)
#pragma unroll
        for (int b = 0; b < 4; ++b) acc[a][b] = zero;

    for (int m0 = 0; m0 < WW; m0 += 32) {
#pragma unroll
        for (int p = 0; p < 2; ++p) {
            const int id  = p * 256 + tid;
            const int row = id >> 2;
            const int c4  = id & 3;
            *(uint4*)&As[row][c4 * 8] =
                *(const uint4*)(w  + (size_t)(i0 + row) * WW + m0 + c4 * 8);
            *(uint4*)&Bs[row][c4 * 8] =
                *(const uint4*)(vt + (size_t)(j0 + row) * WW + m0 + c4 * 8);
        }
        __syncthreads();

        bf16x8 af[4], bfr[4];
#pragma unroll
        for (int t = 0; t < 4; ++t)
            af[t]  = *(const bf16x8*)&As[wy + t * 16 + ml][quad * 8];
#pragma unroll
        for (int t = 0; t < 4; ++t)
            bfr[t] = *(const bf16x8*)&Bs[wx + t * 16 + ml][quad * 8];
#pragma unroll
        for (int a = 0; a < 4; ++a)
#pragma unroll
            for (int b = 0; b < 4; ++b)
                acc[a][b] = __builtin_amdgcn_mfma_f32_16x16x32_bf16(
                    af[a], bfr[b], acc[a][b], 0, 0, 0);
        __syncthreads();
    }

    // C/D layout: col = lane&15, row = quad*4 + reg
#pragma unroll
    for (int a = 0; a < 4; ++a)
#pragma unroll
        for (int b = 0; b < 4; ++b)
#pragma unroll
            for (int r = 0; r < 4; ++r)
                o[(size_t)(i0 + wy + a * 16 + quad * 4 + r) * WW
                  + j0 + wx + b * 16 + ml] = acc[a][b][r];
}

// ---------------------------------------------------------------------------
extern "C" void kernel_launch(void* const* d_in, const int* in_sizes, int n_in,
                              void* d_out, int out_size, void* d_ws, size_t ws_size,
                              hipStream_t stream) {
    const float* x  = (const float*)d_in[0];
    const float* Wq = (const float*)d_in[1];
    const float* bq = (const float*)d_in[2];
    const float* Wk = (const float*)d_in[3];
    const float* bk = (const float*)d_in[4];
    const float* Wv = (const float*)d_in[5];
    const float* bv = (const float*)d_in[6];
    float* out = (float*)d_out;

    // ws layout (402.7 MB):
    //   Qp uint [134MB] | Kp uint [134MB] | Vb bf16 [67MB] | Vt bf16 [67MB]
    //   Qp/Kp layout: per (b,c) slab [h>>3][i][h&7] packed-split uint.
    //   Wb (softmax bf16) aliases Qp — Qp is dead after attn_mfma3.
    const size_t NEL = (size_t)NB * CH * HWS;       // 33,554,432
    uint*   Qp = (uint*)d_ws;
    uint*   Kp = Qp + NEL;
    ushort* Vb = (ushort*)(Kp + NEL);
    ushort* Vt = Vb + NEL;
    ushort* Wb = (ushort*)d_ws;                     // alias Qp

    qkv_mfma2<<<(NB * HWS) / 128, 256, 0, stream>>>(x, Wq, bq, Wk, bk, Wv, bv, Qp, Kp, Vb);
    attn_mfma3<<<NB * CH * 4, 256, 0, stream>>>(Qp, Kp, out);
    transpose_v<<<NB * CH * 4, 256, 0, stream>>>(Vb, Vt);
    softmax_kernel<<<NB * WW, 128, 0, stream>>>(out, Wb);
    pv_kernel2<<<NB * CH * 4, 256, 0, stream>>>(Wb, Vt, out);
}